// Round 4
// baseline (697.184 us; speedup 1.0000x reference)
//
#include <hip/hip_runtime.h>

typedef short bf16x8 __attribute__((ext_vector_type(8)));   // 8 bf16 bit-patterns (4 VGPRs)
typedef float f32x4 __attribute__((ext_vector_type(4)));

#define NROWS 131072L
#define DIN 1024
#define DEMB 512

// f32 -> bf16 RNE bit-twiddle. PROVEN faster than __bf16 casts here (R1=326us vs R3=385us A/B).
__device__ __forceinline__ unsigned short f2bf(float f) {
  unsigned u = __float_as_uint(f);
  u += 0x7FFFu + ((u >> 16) & 1u);     // RNE
  return (unsigned short)(u >> 16);
}

__device__ __forceinline__ float softplusf(float v) {
  return fmaxf(v, 0.f) + log1pf(expf(-fabsf(v)));
}

// ---------- kernel 0: Wb (1024x512 f32) -> WbT (512x1024 bf16) ----------
__global__ __launch_bounds__(256) void wb_transpose(const float* __restrict__ Wb,
                                                    unsigned short* __restrict__ WbT) {
  int g = blockIdx.x * 256 + threadIdx.x;   // 65536 threads
  int n = g & 511;
  int kb = g >> 9;                          // 0..127, 8 k each
  unsigned short tmp[8];
#pragma unroll
  for (int j = 0; j < 8; ++j)
    tmp[j] = f2bf(Wb[(kb * 8 + j) * DEMB + n]);
  uint4 v;
  v.x = (unsigned)tmp[0] | ((unsigned)tmp[1] << 16);
  v.y = (unsigned)tmp[2] | ((unsigned)tmp[3] << 16);
  v.z = (unsigned)tmp[4] | ((unsigned)tmp[5] << 16);
  v.w = (unsigned)tmp[6] | ((unsigned)tmp[7] << 16);
  *(uint4*)(WbT + (long)n * DIN + kb * 8) = v;
}

// ---------- kernel 1: emb = bf16MFMA(x @ WbT^T) + bb ----------
// 128x128 tile, BK=32 (LDS 32 KiB -> 5 blocks/CU, ~62% occupancy), 2x2 waves.
// Swizzle: granule ^= (row>>1)&3 within 64B rows -> 2-way (free) ds_read.
__global__ __launch_bounds__(256, 5) void gemm_bias(const float* __restrict__ x,
                                                    const unsigned short* __restrict__ wbt,
                                                    const float* __restrict__ bb,
                                                    float* __restrict__ emb) {
  __shared__ unsigned short As[2][128 * 32];
  __shared__ unsigned short Bsh[2][128 * 32];

  const int t = threadIdx.x;
  const int lane = t & 63;
  const int wid = t >> 6;
  const int wm = wid >> 1, wn = wid & 1;

  // XCD-aware swizzle (4096 blocks, 4096%8==0 -> simple bijective form).
  const int bid = blockIdx.x;
  const int swz = (bid & 7) * 512 + (bid >> 3);
  const int ntile = swz & 3;
  const long mtile = swz >> 2;
  const long m0 = mtile * 128;
  const int n0 = ntile * 128;

  // ---- A staging: thread t -> row (t>>3)+32p, float4 kc=t&7 (rows dense: 8 lanes/row) ----
  const int arow = t >> 3;                    // 0..31 (+p*32)
  const int akc = t & 7;                      // float4 index within 32-k row
  // LDS byte: row*64 + ((g ^ f(row))<<4) + half*8 ; g=akc>>1, half=akc&1, f(row)=(row>>1)&3
  const int abyte = arow * 64 + ((((akc >> 1) ^ ((t >> 4) & 3)) << 4)) + (akc & 1) * 8;
  const float* xbase = x + (m0 + arow) * DIN + akc * 4;

  // ---- B staging (global_load_lds, pre-swizzled source) ----
  // dest granule d = i*256 + wid*64 + l -> (n = d>>2, gk = d&3); src granule = gk ^ ((n>>1)&3)
  const int bn = wid * 16 + (lane >> 2);                   // +i*64
  const int bsg = (lane & 3) ^ ((lane >> 3) & 3);          // swizzled granule in row
  const unsigned short* bsrc = wbt + (long)(n0 + bn) * DIN + bsg * 8;

  // ---- fragment read offsets: granule = lg ^ ((l15>>1)&3), row stride 64B ----
  const int l15 = lane & 15, lg = lane >> 4;
  const int kgo = ((lg ^ ((l15 >> 1) & 3)) << 4);
  const int ardrow = (wm * 64 + l15) * 64;
  const int brdrow = (wn * 64 + l15) * 64;

  f32x4 acc[4][4] = {};
  float4 areg[4];

  auto loadA = [&](int k0) {
#pragma unroll
    for (int p = 0; p < 4; ++p)
      areg[p] = *(const float4*)(xbase + (long)p * 32 * DIN + k0);
  };
  auto stageB = [&](int b, int k0) {
#pragma unroll
    for (int i = 0; i < 2; ++i) {
      const unsigned short* gp = bsrc + (long)i * 64 * DIN + k0;
      unsigned short* lp = &Bsh[b][(i * 256 + wid * 64) * 8];
      __builtin_amdgcn_global_load_lds(
          (const __attribute__((address_space(1))) void*)gp,
          (__attribute__((address_space(3))) void*)lp, 16, 0, 0);
    }
  };
  auto writeA = [&](int b) {
    char* base = (char*)As[b];
#pragma unroll
    for (int p = 0; p < 4; ++p) {
      ushort4 v;
      v.x = f2bf(areg[p].x); v.y = f2bf(areg[p].y);
      v.z = f2bf(areg[p].z); v.w = f2bf(areg[p].w);
      *(ushort4*)(base + abyte + p * 2048) = v;
    }
  };
  auto compute = [&](int b) {
    const char* Ab = (const char*)As[b];
    const char* Bb = (const char*)Bsh[b];
    bf16x8 af[4], bf_[4];
#pragma unroll
    for (int i = 0; i < 4; ++i) {
      af[i] = *(const bf16x8*)(Ab + ardrow + i * 1024 + kgo);
      bf_[i] = *(const bf16x8*)(Bb + brdrow + i * 1024 + kgo);
    }
#pragma unroll
    for (int mi = 0; mi < 4; ++mi)
#pragma unroll
      for (int ni = 0; ni < 4; ++ni)
        acc[mi][ni] = __builtin_amdgcn_mfma_f32_16x16x32_bf16(af[mi], bf_[ni],
                                                             acc[mi][ni], 0, 0, 0);
  };

  // prologue: stage tile 0
  loadA(0);
  stageB(0, 0);
  writeA(0);
  __syncthreads();

  int buf = 0;
#pragma unroll 1
  for (int tt = 0; tt < 32; ++tt) {
    if (tt + 1 < 32) {
      loadA((tt + 1) * 32);            // issue A loads early (hide under compute)
      stageB(buf ^ 1, (tt + 1) * 32);  // async B -> LDS (in flight across compute)
    }
    compute(buf);
    if (tt + 1 < 32) writeA(buf ^ 1);  // convert+write after compute
    __syncthreads();
    buf ^= 1;
  }

  // epilogue: add bias, store f32
  const int colg = n0 + wn * 64 + l15;
  float bbv[4];
#pragma unroll
  for (int ni = 0; ni < 4; ++ni) bbv[ni] = bb[colg + ni * 16];
#pragma unroll
  for (int mi = 0; mi < 4; ++mi) {
    const long rbase = m0 + wm * 64 + mi * 16 + lg * 4;
#pragma unroll
    for (int ni = 0; ni < 4; ++ni) {
#pragma unroll
      for (int r = 0; r < 4; ++r)
        emb[(rbase + r) * DEMB + colg + ni * 16] = acc[mi][ni][r] + bbv[ni];
    }
  }
}

// ---------- kernel 2: heads (pooled + selected source), one wave per row ----------
__global__ __launch_bounds__(256) void head_kernel(const float* __restrict__ emb,
                                                   const int* __restrict__ sid,
                                                   const float* __restrict__ Wp,
                                                   const float* __restrict__ bp,
                                                   const float* __restrict__ Ws,
                                                   const float* __restrict__ bs,
                                                   float* __restrict__ out) {
  const int t = threadIdx.x;
  const int lane = t & 63;
  const int w = t >> 6;
  const long row = (long)blockIdx.x * 4 + w;
  const float* e = emb + row * DEMB;
  const int s = sid[row];
  const float2* wp2 = (const float2*)Wp;
  const float2* ws2 = (const float2*)(Ws + (long)s * (DEMB * 2));
  float a0 = 0.f, a1 = 0.f, a2 = 0.f, a3 = 0.f;
#pragma unroll
  for (int j = 0; j < 8; ++j) {
    int c = j * 64 + lane;
    float ev = e[c];
    float2 wp = wp2[c];
    float2 wv = ws2[c];
    a0 = fmaf(ev, wp.x, a0);
    a1 = fmaf(ev, wp.y, a1);
    a2 = fmaf(ev, wv.x, a2);
    a3 = fmaf(ev, wv.y, a3);
  }
#pragma unroll
  for (int m = 32; m >= 1; m >>= 1) {
    a0 += __shfl_xor(a0, m);
    a1 += __shfl_xor(a1, m);
    a2 += __shfl_xor(a2, m);
    a3 += __shfl_xor(a3, m);
  }
  if (lane == 0) {
    float* hp = out + NROWS * DEMB;
    hp[row]             = a0 + bp[0];
    hp[NROWS + row]     = softplusf(a1 + bp[1]) + 0.001f;
    hp[2 * NROWS + row] = a2 + bs[s * 2 + 0];
    hp[3 * NROWS + row] = softplusf(a3 + bs[s * 2 + 1]) + 0.001f;
  }
}

extern "C" void kernel_launch(void* const* d_in, const int* in_sizes, int n_in,
                              void* d_out, int out_size, void* d_ws, size_t ws_size,
                              hipStream_t stream) {
  const float* x  = (const float*)d_in[0];
  const int* sid  = (const int*)d_in[1];
  const float* Wb = (const float*)d_in[2];
  const float* bb = (const float*)d_in[3];
  const float* Wp = (const float*)d_in[4];
  const float* bp = (const float*)d_in[5];
  const float* Ws = (const float*)d_in[6];
  const float* bs = (const float*)d_in[7];
  float* out = (float*)d_out;
  unsigned short* WbT = (unsigned short*)d_ws;   // 512*1024*2 = 1 MiB

  wb_transpose<<<256, 256, 0, stream>>>(Wb, WbT);
  gemm_bias<<<4096, 256, 0, stream>>>(x, WbT, bb, out);
  head_kernel<<<32768, 256, 0, stream>>>(out, sid, Wp, bp, Ws, bs, out);
}

// Round 5
// 363.860 us; speedup vs baseline: 1.9161x; 1.9161x over previous
//
#include <hip/hip_runtime.h>

typedef short bf16x8 __attribute__((ext_vector_type(8)));   // 8 bf16 bit-patterns (4 VGPRs)
typedef float f32x4 __attribute__((ext_vector_type(4)));

#define NROWS 131072L
#define DIN 1024
#define DEMB 512

// f32 -> bf16 RNE bit-twiddle (used only in one-time transpose kernel).
__device__ __forceinline__ unsigned short f2bf(float f) {
  unsigned u = __float_as_uint(f);
  u += 0x7FFFu + ((u >> 16) & 1u);     // RNE
  return (unsigned short)(u >> 16);
}

// Pack two f32 -> two bf16 (round-half-up) in one u32: 2 adds + 1 v_perm_b32.
// Cheaper than the 4-instr/elem f2bf chain; max err 0.5 ulp like RNE.
__device__ __forceinline__ unsigned pkhi(float a, float b) {
  unsigned ua = __float_as_uint(a) + 0x8000u;
  unsigned ub = __float_as_uint(b) + 0x8000u;
  // out bytes [ua.b2, ua.b3, ub.b2, ub.b3] ; perm concat = (src0<<32)|src1
  return __builtin_amdgcn_perm(ub, ua, 0x07060302u);
}

__device__ __forceinline__ float softplusf(float v) {
  return fmaxf(v, 0.f) + log1pf(expf(-fabsf(v)));
}

// ---------- kernel 0: Wb (1024x512 f32) -> WbT (512x1024 bf16) ----------
__global__ __launch_bounds__(256) void wb_transpose(const float* __restrict__ Wb,
                                                    unsigned short* __restrict__ WbT) {
  int g = blockIdx.x * 256 + threadIdx.x;   // 65536 threads
  int n = g & 511;
  int kb = g >> 9;                          // 0..127, 8 k each
  unsigned short tmp[8];
#pragma unroll
  for (int j = 0; j < 8; ++j)
    tmp[j] = f2bf(Wb[(kb * 8 + j) * DEMB + n]);
  uint4 v;
  v.x = (unsigned)tmp[0] | ((unsigned)tmp[1] << 16);
  v.y = (unsigned)tmp[2] | ((unsigned)tmp[3] << 16);
  v.z = (unsigned)tmp[4] | ((unsigned)tmp[5] << 16);
  v.w = (unsigned)tmp[6] | ((unsigned)tmp[7] << 16);
  *(uint4*)(WbT + (long)n * DIN + kb * 8) = v;
}

// ---------- kernel 1: emb = bf16MFMA(x @ WbT^T) + bb ----------
// 128x128 tile, BK=32 (LDS 32 KiB), 2x2 waves. launch_bounds(256,3): VGPR cap
// 170 (no spill — R4's (256,5) cap=102 spilled acc -> 0.9GB scratch traffic).
// Swizzle: granule ^= (row>>1)&3 within 64B rows (R4-proven, 0 conflicts).
__global__ __launch_bounds__(256, 3) void gemm_bias(const float* __restrict__ x,
                                                    const unsigned short* __restrict__ wbt,
                                                    const float* __restrict__ bb,
                                                    float* __restrict__ emb) {
  __shared__ unsigned short As[2][128 * 32];
  __shared__ unsigned short Bsh[2][128 * 32];

  const int t = threadIdx.x;
  const int lane = t & 63;
  const int wid = t >> 6;
  const int wm = wid >> 1, wn = wid & 1;

  // XCD-aware swizzle (4096 blocks, 4096%8==0 -> simple bijective form).
  const int bid = blockIdx.x;
  const int swz = (bid & 7) * 512 + (bid >> 3);
  const int ntile = swz & 3;
  const long mtile = swz >> 2;
  const long m0 = mtile * 128;
  const int n0 = ntile * 128;

  // ---- A staging: thread t -> row (t>>3)+32p, float4 kc=t&7 (8 lanes/row, dense 1KB/instr) ----
  const int arow = t >> 3;                    // 0..31 (+p*32)
  const int akc = t & 7;                      // float4 index within 32-k row
  const int abyte = arow * 64 + ((((akc >> 1) ^ ((t >> 4) & 3)) << 4)) + (akc & 1) * 8;
  const float* xbase = x + (m0 + arow) * DIN + akc * 4;

  // ---- B staging (global_load_lds, pre-swizzled source) ----
  const int bn = wid * 16 + (lane >> 2);                   // +i*64
  const int bsg = (lane & 3) ^ ((lane >> 3) & 3);          // swizzled granule in row
  const unsigned short* bsrc = wbt + (long)(n0 + bn) * DIN + bsg * 8;

  // ---- fragment read offsets: granule = lg ^ ((l15>>1)&3), row stride 64B ----
  const int l15 = lane & 15, lg = lane >> 4;
  const int kgo = ((lg ^ ((l15 >> 1) & 3)) << 4);
  const int ardrow = (wm * 64 + l15) * 64;
  const int brdrow = (wn * 64 + l15) * 64;

  f32x4 acc[4][4] = {};
  float4 areg[4];

  auto loadA = [&](int k0) {
#pragma unroll
    for (int p = 0; p < 4; ++p)
      areg[p] = *(const float4*)(xbase + (long)p * 32 * DIN + k0);
  };
  auto stageB = [&](int b, int k0) {
#pragma unroll
    for (int i = 0; i < 2; ++i) {
      const unsigned short* gp = bsrc + (long)i * 64 * DIN + k0;
      unsigned short* lp = &Bsh[b][(i * 256 + wid * 64) * 8];
      __builtin_amdgcn_global_load_lds(
          (const __attribute__((address_space(1))) void*)gp,
          (__attribute__((address_space(3))) void*)lp, 16, 0, 0);
    }
  };
  auto writeA = [&](int b) {
    char* base = (char*)As[b];
#pragma unroll
    for (int p = 0; p < 4; ++p) {
      uint2 v;
      v.x = pkhi(areg[p].x, areg[p].y);
      v.y = pkhi(areg[p].z, areg[p].w);
      *(uint2*)(base + abyte + p * 2048) = v;
    }
  };
  auto compute = [&](int b) {
    const char* Ab = (const char*)As[b];
    const char* Bb = (const char*)Bsh[b];
    bf16x8 af[4], bf_[4];
#pragma unroll
    for (int i = 0; i < 4; ++i) {
      af[i] = *(const bf16x8*)(Ab + ardrow + i * 1024 + kgo);
      bf_[i] = *(const bf16x8*)(Bb + brdrow + i * 1024 + kgo);
    }
#pragma unroll
    for (int mi = 0; mi < 4; ++mi)
#pragma unroll
      for (int ni = 0; ni < 4; ++ni)
        acc[mi][ni] = __builtin_amdgcn_mfma_f32_16x16x32_bf16(af[mi], bf_[ni],
                                                             acc[mi][ni], 0, 0, 0);
  };

  // prologue: stage tile 0
  loadA(0);
  stageB(0, 0);
  writeA(0);
  __syncthreads();

  int buf = 0;
#pragma unroll 1
  for (int tt = 0; tt < 32; ++tt) {
    if (tt + 1 < 32) {
      loadA((tt + 1) * 32);            // issue A loads early (hide under compute)
      stageB(buf ^ 1, (tt + 1) * 32);  // async B -> LDS (in flight across compute)
    }
    compute(buf);
    if (tt + 1 < 32) writeA(buf ^ 1);  // convert+write after compute
    __syncthreads();
    buf ^= 1;
  }

  // epilogue: add bias, store f32
  const int colg = n0 + wn * 64 + l15;
  float bbv[4];
#pragma unroll
  for (int ni = 0; ni < 4; ++ni) bbv[ni] = bb[colg + ni * 16];
#pragma unroll
  for (int mi = 0; mi < 4; ++mi) {
    const long rbase = m0 + wm * 64 + mi * 16 + lg * 4;
#pragma unroll
    for (int ni = 0; ni < 4; ++ni) {
#pragma unroll
      for (int r = 0; r < 4; ++r)
        emb[(rbase + r) * DEMB + colg + ni * 16] = acc[mi][ni][r] + bbv[ni];
    }
  }
}

// ---------- kernel 2: heads (pooled + selected source), one wave per row ----------
__global__ __launch_bounds__(256) void head_kernel(const float* __restrict__ emb,
                                                   const int* __restrict__ sid,
                                                   const float* __restrict__ Wp,
                                                   const float* __restrict__ bp,
                                                   const float* __restrict__ Ws,
                                                   const float* __restrict__ bs,
                                                   float* __restrict__ out) {
  const int t = threadIdx.x;
  const int lane = t & 63;
  const int w = t >> 6;
  const long row = (long)blockIdx.x * 4 + w;
  const float* e = emb + row * DEMB;
  const int s = sid[row];
  const float2* wp2 = (const float2*)Wp;
  const float2* ws2 = (const float2*)(Ws + (long)s * (DEMB * 2));
  float a0 = 0.f, a1 = 0.f, a2 = 0.f, a3 = 0.f;
#pragma unroll
  for (int j = 0; j < 8; ++j) {
    int c = j * 64 + lane;
    float ev = e[c];
    float2 wp = wp2[c];
    float2 wv = ws2[c];
    a0 = fmaf(ev, wp.x, a0);
    a1 = fmaf(ev, wp.y, a1);
    a2 = fmaf(ev, wv.x, a2);
    a3 = fmaf(ev, wv.y, a3);
  }
#pragma unroll
  for (int m = 32; m >= 1; m >>= 1) {
    a0 += __shfl_xor(a0, m);
    a1 += __shfl_xor(a1, m);
    a2 += __shfl_xor(a2, m);
    a3 += __shfl_xor(a3, m);
  }
  if (lane == 0) {
    float* hp = out + NROWS * DEMB;
    hp[row]             = a0 + bp[0];
    hp[NROWS + row]     = softplusf(a1 + bp[1]) + 0.001f;
    hp[2 * NROWS + row] = a2 + bs[s * 2 + 0];
    hp[3 * NROWS + row] = softplusf(a3 + bs[s * 2 + 1]) + 0.001f;
  }
}

extern "C" void kernel_launch(void* const* d_in, const int* in_sizes, int n_in,
                              void* d_out, int out_size, void* d_ws, size_t ws_size,
                              hipStream_t stream) {
  const float* x  = (const float*)d_in[0];
  const int* sid  = (const int*)d_in[1];
  const float* Wb = (const float*)d_in[2];
  const float* bb = (const float*)d_in[3];
  const float* Wp = (const float*)d_in[4];
  const float* bp = (const float*)d_in[5];
  const float* Ws = (const float*)d_in[6];
  const float* bs = (const float*)d_in[7];
  float* out = (float*)d_out;
  unsigned short* WbT = (unsigned short*)d_ws;   // 512*1024*2 = 1 MiB

  wb_transpose<<<256, 256, 0, stream>>>(Wb, WbT);
  gemm_bias<<<4096, 256, 0, stream>>>(x, WbT, bb, out);
  head_kernel<<<32768, 256, 0, stream>>>(out, sid, Wp, bp, Ws, bs, out);
}

// Round 6
// 360.550 us; speedup vs baseline: 1.9337x; 1.0092x over previous
//
#include <hip/hip_runtime.h>

typedef short bf16x8 __attribute__((ext_vector_type(8)));
typedef float f32x4 __attribute__((ext_vector_type(4)));

#define NROWS 131072L
#define DIN 1024
#define DEMB 512
#define NEXT 640   // extended B rows: 512 emb + 34 folded-head + 94 zero

// f32 -> bf16 RNE bit-twiddle (R1-proven faster than __bf16 casts here).
__device__ __forceinline__ unsigned short f2bf(float f) {
  unsigned u = __float_as_uint(f);
  u += 0x7FFFu + ((u >> 16) & 1u);
  return (unsigned short)(u >> 16);
}

// Pack two f32 -> two bf16 (round-half-up): 2 adds + 1 v_perm_b32 (R5-proven).
__device__ __forceinline__ unsigned pkhi(float a, float b) {
  unsigned ua = __float_as_uint(a) + 0x8000u;
  unsigned ub = __float_as_uint(b) + 0x8000u;
  return __builtin_amdgcn_perm(ub, ua, 0x07060302u);
}

__device__ __forceinline__ float softplusf(float v) {
  return fmaxf(v, 0.f) + log1pf(expf(-fabsf(v)));
}

// ---------- kernel 0: Wb (1024x512 f32) -> WbT rows 0..511 (bf16, k-contig) ----------
__global__ __launch_bounds__(256) void wb_transpose(const float* __restrict__ Wb,
                                                    unsigned short* __restrict__ WbT) {
  int g = blockIdx.x * 256 + threadIdx.x;
  int n = g & 511;
  int kb = g >> 9;
  unsigned short tmp[8];
#pragma unroll
  for (int j = 0; j < 8; ++j)
    tmp[j] = f2bf(Wb[(kb * 8 + j) * DEMB + n]);
  uint4 v;
  v.x = (unsigned)tmp[0] | ((unsigned)tmp[1] << 16);
  v.y = (unsigned)tmp[2] | ((unsigned)tmp[3] << 16);
  v.z = (unsigned)tmp[4] | ((unsigned)tmp[5] << 16);
  v.w = (unsigned)tmp[6] | ((unsigned)tmp[7] << 16);
  *(uint4*)(WbT + (long)n * DIN + kb * 8) = v;
}

// ---------- kernel 0b: zero rows 546..639 of WbT_ext ----------
__global__ void zero_tail(unsigned* __restrict__ p) {
  p[blockIdx.x * 256 + threadIdx.x] = 0u;   // 188*256 = 48128 u32 = 94 rows * 1024 bf16
}

// ---------- kernel 0c: WbT rows 512..545 = (Wb @ W34)^T  (head-weight fold) ----------
// W34 col j: j=0,1 -> Wp[:,j]; j=2+2s+jj -> Ws[s][:,jj]
__global__ __launch_bounds__(256) void wfold_rows(const float* __restrict__ Wb,
                                                  const float* __restrict__ Wp,
                                                  const float* __restrict__ Ws,
                                                  unsigned short* __restrict__ WbT) {
  int w = threadIdx.x >> 6, lane = threadIdx.x & 63;
  int k = blockIdx.x * 4 + w;                       // 256 blocks * 4 waves = 1024 k-rows
  if (lane >= 34) return;
  const float* src;
  if (lane < 2) src = Wp + lane;
  else { int s = (lane - 2) >> 1; src = Ws + s * 1024 + (lane & 1); }
  const float* wrow = Wb + (long)k * DEMB;          // broadcast reads (all lanes same addr)
  float acc = 0.f;
#pragma unroll 8
  for (int d = 0; d < DEMB; ++d) acc = fmaf(wrow[d], src[2 * d], acc);
  WbT[(long)(512 + lane) * DIN + k] = f2bf(acc);
}

// ---------- kernel 0d: bfold[j] = bb @ W34[:,j] + bias34[j] ----------
__global__ void bfold_k(const float* __restrict__ bb, const float* __restrict__ Wp,
                        const float* __restrict__ bp, const float* __restrict__ Ws,
                        const float* __restrict__ bs, float* __restrict__ bf) {
  int j = threadIdx.x;
  if (j >= 34) return;
  const float* src; float bias;
  if (j < 2) { src = Wp + j; bias = bp[j]; }
  else { int s = (j - 2) >> 1; src = Ws + s * 1024 + (j & 1); bias = bs[s * 2 + (j & 1)]; }
  float acc = bias;
  for (int d = 0; d < DEMB; ++d) acc = fmaf(bb[d], src[2 * d], acc);
  bf[j] = acc;
}

// ---------- kernel 1: fused GEMM: emb (ntile<4) + heads (ntile==4) ----------
// 128x128 tile, BK=32, 2x2 waves. 2-deep A prefetch + counted vmcnt(4) raw
// s_barrier: next-next A loads stay in flight ACROSS the barrier (T3/T4-lite).
__global__ __launch_bounds__(256, 3) void gemm_fused(
    const float* __restrict__ x, const unsigned short* __restrict__ wbt,
    const float* __restrict__ bb, const int* __restrict__ sid,
    const float* __restrict__ bfold, float* __restrict__ out) {
  __shared__ unsigned short SM[16384];   // 32 KiB: As0|As1|Bs0|Bs1 (8 KiB each)
  unsigned short* const As0 = SM;
  unsigned short* const As1 = SM + 4096;
  unsigned short* const Bs0 = SM + 8192;
  unsigned short* const Bs1 = SM + 12288;

  const int t = threadIdx.x;
  const int lane = t & 63;
  const int wid = t >> 6;
  const int wm = wid >> 1, wn = wid & 1;

  // XCD swizzle: 5120 blocks (%8==0), consecutive swz share mtile (x-panel L2 reuse)
  const int bid = blockIdx.x;
  const int swz = (bid & 7) * 640 + (bid >> 3);
  const int mtile = swz / 5;
  const int ntile = swz - mtile * 5;
  const long m0 = (long)mtile * 128;
  const int n0 = ntile * 128;

  // A staging: row = t>>3 (+32p), float4 kc = t&7; swizzle granule ^= (row>>1)&3
  const int arow = t >> 3;
  const int akc = t & 7;
  const int abyte = arow * 64 + ((((akc >> 1) ^ ((t >> 4) & 3)) << 4)) + (akc & 1) * 8;
  const float* xbase = x + (m0 + arow) * DIN + akc * 4;

  // B staging (global_load_lds, pre-swizzled source)
  const int bn = wid * 16 + (lane >> 2);
  const int bsg = (lane & 3) ^ ((lane >> 3) & 3);
  const unsigned short* bsrc = wbt + (long)(n0 + bn) * DIN + bsg * 8;

  // fragment reads: granule = lg ^ ((l15>>1)&3), 64B rows
  const int l15 = lane & 15, lg = lane >> 4;
  const int kgo = ((lg ^ ((l15 >> 1) & 3)) << 4);
  const int ardrow = (wm * 64 + l15) * 64;
  const int brdrow = (wn * 64 + l15) * 64;

  f32x4 acc[4][4] = {};
  float4 aregA[4], aregB[4];

  auto loadA_A = [&](int k0) {
#pragma unroll
    for (int p = 0; p < 4; ++p)
      aregA[p] = *(const float4*)(xbase + (long)p * 32 * DIN + k0);
  };
  auto loadA_B = [&](int k0) {
#pragma unroll
    for (int p = 0; p < 4; ++p)
      aregB[p] = *(const float4*)(xbase + (long)p * 32 * DIN + k0);
  };
  auto stageB = [&](unsigned short* dst, int k0) {
#pragma unroll
    for (int i = 0; i < 2; ++i) {
      const unsigned short* gp = bsrc + (long)i * 64 * DIN + k0;
      unsigned short* lp = dst + (i * 256 + wid * 64) * 8;   // wave-uniform base
      __builtin_amdgcn_global_load_lds(
          (const __attribute__((address_space(1))) void*)gp,
          (__attribute__((address_space(3))) void*)lp, 16, 0, 0);
    }
  };
  auto writeA_0A = [&]() {
    char* base = (char*)As0;
#pragma unroll
    for (int p = 0; p < 4; ++p) {
      uint2 v; v.x = pkhi(aregA[p].x, aregA[p].y); v.y = pkhi(aregA[p].z, aregA[p].w);
      *(uint2*)(base + abyte + p * 2048) = v;
    }
  };
  auto writeA_1B = [&]() {
    char* base = (char*)As1;
#pragma unroll
    for (int p = 0; p < 4; ++p) {
      uint2 v; v.x = pkhi(aregB[p].x, aregB[p].y); v.y = pkhi(aregB[p].z, aregB[p].w);
      *(uint2*)(base + abyte + p * 2048) = v;
    }
  };
  auto compute = [&](const unsigned short* Au, const unsigned short* Bu) {
    const char* Ab = (const char*)Au;
    const char* Bb = (const char*)Bu;
    bf16x8 af[4], bfv[4];
#pragma unroll
    for (int i = 0; i < 4; ++i) {
      af[i] = *(const bf16x8*)(Ab + ardrow + i * 1024 + kgo);
      bfv[i] = *(const bf16x8*)(Bb + brdrow + i * 1024 + kgo);
    }
#pragma unroll
    for (int mi = 0; mi < 4; ++mi)
#pragma unroll
      for (int ni = 0; ni < 4; ++ni)
        acc[mi][ni] = __builtin_amdgcn_mfma_f32_16x16x32_bf16(af[mi], bfv[ni],
                                                             acc[mi][ni], 0, 0, 0);
  };

  // ---- prologue: tile0 staged+written; tile1 A-loads left in flight ----
  stageB(Bs0, 0);
  loadA_A(0);
  writeA_0A();                       // compiler auto-waits the A loads
  loadA_B(32);
  __builtin_amdgcn_sched_barrier(0);
  asm volatile("s_waitcnt vmcnt(4) lgkmcnt(0)" ::: "memory");  // drain stageB, keep loadA(1)
  __builtin_amdgcn_sched_barrier(0);
  __builtin_amdgcn_s_barrier();

#pragma unroll 1
  for (int it = 0; it < 15; ++it) {
    const int ke = it * 2;           // even tile index 0..28
    // even: compute tile ke from buf0; stage ke+1; prefetch A ke+2
    stageB(Bs1, (ke + 1) * 32);
    __builtin_amdgcn_sched_barrier(0);   // pin: stageB older than loadA (vmcnt FIFO)
    loadA_A((ke + 2) * 32);
    compute(As0, Bs0);
    writeA_1B();                     // tile ke+1 (auto vmcnt(6): waits only its loads)
    __builtin_amdgcn_sched_barrier(0);
    asm volatile("s_waitcnt vmcnt(4) lgkmcnt(0)" ::: "memory");  // drain stageB, keep loadA
    __builtin_amdgcn_sched_barrier(0);
    __builtin_amdgcn_s_barrier();
    // odd: compute tile ke+1 from buf1; stage ke+2; prefetch A ke+3
    stageB(Bs0, (ke + 2) * 32);
    __builtin_amdgcn_sched_barrier(0);
    loadA_B((ke + 3) * 32);
    compute(As1, Bs1);
    writeA_0A();                     // tile ke+2
    __builtin_amdgcn_sched_barrier(0);
    asm volatile("s_waitcnt vmcnt(4) lgkmcnt(0)" ::: "memory");
    __builtin_amdgcn_sched_barrier(0);
    __builtin_amdgcn_s_barrier();
  }

  // tt = 30: stage tile31; compute tile30; write tile31
  stageB(Bs1, 31 * 32);
  compute(As0, Bs0);
  writeA_1B();
  __builtin_amdgcn_sched_barrier(0);
  asm volatile("s_waitcnt vmcnt(0) lgkmcnt(0)" ::: "memory");
  __builtin_amdgcn_sched_barrier(0);
  __builtin_amdgcn_s_barrier();
  // tt = 31
  compute(As1, Bs1);

  // ---- epilogue ----
  if (ntile < 4) {
    const int colg = n0 + wn * 64 + l15;
    float bbv[4];
#pragma unroll
    for (int ni = 0; ni < 4; ++ni) bbv[ni] = bb[colg + ni * 16];
#pragma unroll
    for (int mi = 0; mi < 4; ++mi) {
      const long rbase = m0 + wm * 64 + mi * 16 + lg * 4;
#pragma unroll
      for (int ni = 0; ni < 4; ++ni)
#pragma unroll
        for (int r = 0; r < 4; ++r)
          out[(rbase + r) * DEMB + colg + ni * 16] = acc[mi][ni][r] + bbv[ni];
    }
  } else {
    // head tile: acc cols 0..33 are x@Wfold; gather per-row selected cols via LDS
    __syncthreads();
    float* hl = (float*)SM;          // [128][49] f32 = 25 KiB
    if (wn == 0) {
#pragma unroll
      for (int ni = 0; ni < 3; ++ni)
#pragma unroll
        for (int mi = 0; mi < 4; ++mi)
#pragma unroll
          for (int r = 0; r < 4; ++r) {
            int row = wm * 64 + mi * 16 + lg * 4 + r;
            hl[row * 49 + l15 + ni * 16] = acc[mi][ni][r];
          }
    }
    __syncthreads();
    if (t < 128) {
      const long row = m0 + t;
      const int s = sid[row];
      const float v0 = hl[t * 49 + 0] + bfold[0];
      const float v1 = hl[t * 49 + 1] + bfold[1];
      const float v2 = hl[t * 49 + 2 + 2 * s] + bfold[2 + 2 * s];
      const float v3 = hl[t * 49 + 3 + 2 * s] + bfold[3 + 2 * s];
      float* hp = out + NROWS * DEMB;
      hp[row] = v0;
      hp[NROWS + row] = softplusf(v1) + 0.001f;
      hp[2 * NROWS + row] = v2;
      hp[3 * NROWS + row] = softplusf(v3) + 0.001f;
    }
  }
}

extern "C" void kernel_launch(void* const* d_in, const int* in_sizes, int n_in,
                              void* d_out, int out_size, void* d_ws, size_t ws_size,
                              hipStream_t stream) {
  const float* x  = (const float*)d_in[0];
  const int* sid  = (const int*)d_in[1];
  const float* Wb = (const float*)d_in[2];
  const float* bb = (const float*)d_in[3];
  const float* Wp = (const float*)d_in[4];
  const float* bp = (const float*)d_in[5];
  const float* Ws = (const float*)d_in[6];
  const float* bs = (const float*)d_in[7];
  float* out = (float*)d_out;
  unsigned short* WbT = (unsigned short*)d_ws;            // 640*1024 bf16 = 1.25 MiB
  float* bfoldp = (float*)(WbT + (long)NEXT * DIN);       // 34 f32

  wb_transpose<<<256, 256, 0, stream>>>(Wb, WbT);
  zero_tail<<<188, 256, 0, stream>>>((unsigned*)(WbT + 546 * DIN));
  wfold_rows<<<256, 256, 0, stream>>>(Wb, Wp, Ws, WbT);
  bfold_k<<<1, 64, 0, stream>>>(bb, Wp, bp, Ws, bs, bfoldp);
  gemm_fused<<<5120, 256, 0, stream>>>(x, WbT, bb, sid, bfoldp, out);
}